// Round 2
// baseline (1963.829 us; speedup 1.0000x reference)
//
#include <hip/hip_runtime.h>

#define K_DIM 4096
#define N_DIM 11008
#define NPACK (N_DIM / 8)   // 1376 packed int32 per k-row
#define BM 128
#define BN 128
#define BK 32

typedef __bf16 bf16x8 __attribute__((ext_vector_type(8)));
typedef float f32x4 __attribute__((ext_vector_type(4)));
typedef unsigned short u16x8 __attribute__((ext_vector_type(8)));

// fp32 -> bf16 bits, round-to-nearest-even (finite inputs only)
__device__ __forceinline__ unsigned short f2bf(float f) {
    unsigned u = __builtin_bit_cast(unsigned, f);
    return (unsigned short)((u + 0x7FFFu + ((u >> 16) & 1u)) >> 16);
}
__device__ __forceinline__ unsigned pack2bf(float a, float b) {
    return (unsigned)f2bf(a) | ((unsigned)f2bf(b) << 16);
}

// 128x128 tile, 256 threads (4 waves, 2x2 of 64x64 wave-tiles), BK=32.
// A = x (fp32 -> bf16 on stage-in), B = dequantized int4 weights.
__global__ __launch_bounds__(256, 2)
void l4b_mfma(const float* __restrict__ x, const int* __restrict__ qw,
              const float* __restrict__ scales, const int* __restrict__ qz,
              const float* __restrict__ bias, float* __restrict__ out)
{
    __shared__ unsigned short As[BM][BK];   // bf16 bits, [m][k] : 8 KB
    __shared__ unsigned short Bs[BK][BN];   // bf16 bits, [k][n] : 8 KB

    const int tid = threadIdx.x;
    const int bn0 = blockIdx.x * BN;
    const int bm0 = blockIdx.y * BM;

    // ---- A staging geometry: 32 floats/row, 8 threads/row, 4 row-passes ----
    const int ar = tid >> 3;          // 0..31
    const int ac = (tid & 7) << 2;    // 0,4,...,28
    // ---- B staging geometry: 16 packed ints/row, 2 k-row passes ----
    const int bng = tid & 15;         // packed-int column within tile
    const int bkr = tid >> 4;         // 0..15 -> k-rows bkr, bkr+16
    const int nq  = (bn0 >> 3) + bng; // column in qweight

    // per-thread dequant constants for its 8 output columns (loop-invariant)
    float s8[8], zs8[8];
    {
        const unsigned zq = (unsigned)qz[nq];
        const float4 slo = *reinterpret_cast<const float4*>(scales + bn0 + bng * 8);
        const float4 shi = *reinterpret_cast<const float4*>(scales + bn0 + bng * 8 + 4);
        s8[0] = slo.x; s8[1] = slo.y; s8[2] = slo.z; s8[3] = slo.w;
        s8[4] = shi.x; s8[5] = shi.y; s8[6] = shi.z; s8[7] = shi.w;
        #pragma unroll
        for (int j = 0; j < 8; ++j)
            zs8[j] = (float)((zq >> (4 * j)) & 0xFu) * s8[j];
    }

    const int lane = tid & 63;
    const int wv   = tid >> 6;
    const int quad = lane >> 4;
    const int l16  = lane & 15;
    const int wm   = (wv >> 1) * 64;   // wave m-offset within tile
    const int wn   = (wv & 1) * 64;    // wave n-offset within tile

    f32x4 acc[4][4] = {};

    for (int k0 = 0; k0 < K_DIM; k0 += BK) {
        __syncthreads();   // previous iteration's reads done before overwrite

        // ---- stage A: fp32 -> bf16 into As[m][k] ----
        #pragma unroll
        for (int p = 0; p < 4; ++p) {
            const int row = ar + p * 32;
            const float4 v = *reinterpret_cast<const float4*>(
                x + (size_t)(bm0 + row) * K_DIM + (k0 + ac));
            *reinterpret_cast<unsigned*>(&As[row][ac])     = pack2bf(v.x, v.y);
            *reinterpret_cast<unsigned*>(&As[row][ac + 2]) = pack2bf(v.z, v.w);
        }

        // ---- stage B: unpack+dequant 2 packed ints -> Bs[k][n] ----
        #pragma unroll
        for (int p = 0; p < 2; ++p) {
            const int kk = bkr + p * 16;
            const unsigned q  = (unsigned)qw[(size_t)(k0 + kk) * NPACK + nq];
            const unsigned qe = q & 0x0F0F0F0Fu;          // even nibbles
            const unsigned qo = (q >> 4) & 0x0F0F0F0Fu;   // odd nibbles
            float f[8];
            f[0] = (float)(qe & 0xFFu);
            f[1] = (float)(qo & 0xFFu);
            f[2] = (float)((qe >> 8) & 0xFFu);
            f[3] = (float)((qo >> 8) & 0xFFu);
            f[4] = (float)((qe >> 16) & 0xFFu);
            f[5] = (float)((qo >> 16) & 0xFFu);
            f[6] = (float)((qe >> 24) & 0xFFu);
            f[7] = (float)((qo >> 24) & 0xFFu);
            #pragma unroll
            for (int j = 0; j < 4; ++j) {
                const float w0 = fmaf(f[2 * j],     s8[2 * j],     -zs8[2 * j]);
                const float w1 = fmaf(f[2 * j + 1], s8[2 * j + 1], -zs8[2 * j + 1]);
                *reinterpret_cast<unsigned*>(&Bs[kk][bng * 8 + 2 * j]) = pack2bf(w0, w1);
            }
        }

        __syncthreads();

        // ---- fragments + MFMA ----
        bf16x8 af[4], bfr[4];
        #pragma unroll
        for (int mi = 0; mi < 4; ++mi)
            af[mi] = *reinterpret_cast<const bf16x8*>(&As[wm + mi * 16 + l16][quad * 8]);
        #pragma unroll
        for (int ni = 0; ni < 4; ++ni) {
            u16x8 bu;
            #pragma unroll
            for (int jj = 0; jj < 8; ++jj)
                bu[jj] = Bs[quad * 8 + jj][wn + ni * 16 + l16];
            bfr[ni] = __builtin_bit_cast(bf16x8, bu);
        }
        #pragma unroll
        for (int mi = 0; mi < 4; ++mi) {
            #pragma unroll
            for (int ni = 0; ni < 4; ++ni)
                acc[mi][ni] = __builtin_amdgcn_mfma_f32_16x16x32_bf16(
                    af[mi], bfr[ni], acc[mi][ni], 0, 0, 0);
        }
    }

    // ---- epilogue: D[m=quad*4+r][n=l16] per verified C/D layout ----
    #pragma unroll
    for (int ni = 0; ni < 4; ++ni) {
        const int n = bn0 + wn + ni * 16 + l16;
        const float bv = bias[n];
        #pragma unroll
        for (int mi = 0; mi < 4; ++mi) {
            #pragma unroll
            for (int r = 0; r < 4; ++r) {
                const int m = bm0 + wm + mi * 16 + quad * 4 + r;
                out[(size_t)m * N_DIM + n] = acc[mi][ni][r] + bv;
            }
        }
    }
}

extern "C" void kernel_launch(void* const* d_in, const int* in_sizes, int n_in,
                              void* d_out, int out_size, void* d_ws, size_t ws_size,
                              hipStream_t stream)
{
    (void)n_in; (void)out_size; (void)d_ws; (void)ws_size;
    const float* x      = (const float*)d_in[0];
    const int*   qw     = (const int*)d_in[1];
    const float* scales = (const float*)d_in[2];
    const int*   qz     = (const int*)d_in[3];
    const float* bias   = (const float*)d_in[4];
    float* out = (float*)d_out;

    const int M = in_sizes[0] / K_DIM;          // 8192
    dim3 grid(N_DIM / BN, M / BM);              // (86, 64)
    l4b_mfma<<<grid, dim3(256, 1, 1), 0, stream>>>(x, qw, scales, qz, bias, out);
}

// Round 3
// 1721.036 us; speedup vs baseline: 1.1411x; 1.1411x over previous
//
#include <hip/hip_runtime.h>

#define K_DIM 4096
#define N_DIM 11008
#define NPACK (N_DIM / 8)   // 1376 packed int32 per k-row
#define BM 128
#define BN 128
#define BK 32

typedef __bf16 bf16x8 __attribute__((ext_vector_type(8)));
typedef float f32x4 __attribute__((ext_vector_type(4)));
typedef unsigned short u16x8 __attribute__((ext_vector_type(8)));

// fp32 -> bf16 bits, round-to-nearest-even (finite inputs only)
__device__ __forceinline__ unsigned short f2bf(float f) {
    unsigned u = __builtin_bit_cast(unsigned, f);
    return (unsigned short)((u + 0x7FFFu + ((u >> 16) & 1u)) >> 16);
}
__device__ __forceinline__ unsigned pack2bf(float a, float b) {
    return (unsigned)f2bf(a) | ((unsigned)f2bf(b) << 16);
}

// async global->LDS, 16B per lane; LDS dest = wave-uniform base + lane*16
#define GLD16(gp, lp) __builtin_amdgcn_global_load_lds(                       \
    (const __attribute__((address_space(1))) void*)(gp),                      \
    (__attribute__((address_space(3))) void*)(lp), 16, 0, 0)

// ---------------------------------------------------------------------------
// Prepass 1: x fp32 [M][K] -> bf16 [M][K]. 8 elements/thread.
__global__ __launch_bounds__(256)
void convert_x(const float* __restrict__ x, unsigned short* __restrict__ xb)
{
    const size_t i = ((size_t)blockIdx.x * 256 + threadIdx.x) * 8;
    const float4 v0 = *reinterpret_cast<const float4*>(x + i);
    const float4 v1 = *reinterpret_cast<const float4*>(x + i + 4);
    u16x8 o;
    o[0] = f2bf(v0.x); o[1] = f2bf(v0.y); o[2] = f2bf(v0.z); o[3] = f2bf(v0.w);
    o[4] = f2bf(v1.x); o[5] = f2bf(v1.y); o[6] = f2bf(v1.z); o[7] = f2bf(v1.w);
    *reinterpret_cast<u16x8*>(xb + i) = o;
}

// ---------------------------------------------------------------------------
// Prepass 2: dequant int4 W[k][n] -> bf16 Wt[n][k] (transposed), 64x64 tiles.
__global__ __launch_bounds__(256)
void dequant_w(const int* __restrict__ qw, const float* __restrict__ scales,
               const int* __restrict__ qz, unsigned short* __restrict__ wt)
{
    __shared__ unsigned short T[64][76];   // [k][n], +12 pad halves col-read conflicts
    const int n0 = blockIdx.x * 64;
    const int k0 = blockIdx.y * 64;
    const int tid = threadIdx.x;

    #pragma unroll
    for (int h = 0; h < 2; ++h) {
        const int ii = tid + h * 256;            // [0,512): 64 k-rows x 8 packed ints
        const int kl = ii >> 3;
        const int nq = ii & 7;
        const unsigned q  = (unsigned)qw[(size_t)(k0 + kl) * NPACK + (n0 >> 3) + nq];
        const unsigned zq = (unsigned)qz[(n0 >> 3) + nq];
        const float4 s0 = *reinterpret_cast<const float4*>(scales + n0 + nq * 8);
        const float4 s1 = *reinterpret_cast<const float4*>(scales + n0 + nq * 8 + 4);
        const float s[8] = {s0.x, s0.y, s0.z, s0.w, s1.x, s1.y, s1.z, s1.w};
        u16x8 o;
        #pragma unroll
        for (int j = 0; j < 8; ++j) {
            const int   nib = (int)((q  >> (4 * j)) & 0xFu);
            const int   zp  = (int)((zq >> (4 * j)) & 0xFu);
            o[j] = f2bf((float)(nib - zp) * s[j]);
        }
        *reinterpret_cast<u16x8*>(&T[kl][nq * 8]) = o;
    }
    __syncthreads();
    #pragma unroll
    for (int h = 0; h < 2; ++h) {
        const int oo = tid + h * 256;            // [0,512): 64 n-rows x 8 k-chunks
        const int nl = oo >> 3;
        const int c  = oo & 7;
        u16x8 o;
        #pragma unroll
        for (int r = 0; r < 8; ++r) o[r] = T[c * 8 + r][nl];
        *reinterpret_cast<u16x8*>(wt + (size_t)(n0 + nl) * K_DIM + k0 + c * 8) = o;
    }
}

// ---------------------------------------------------------------------------
// Main GEMM: A bf16 [M][K], B bf16 [N][K] (both k-contiguous), out fp32 [M][N].
// 128x128 tile, 4 waves (2x2 of 64x64), BK=32, global_load_lds staging.
__global__ __launch_bounds__(256, 2)
void gemm_bt(const unsigned short* __restrict__ A, const unsigned short* __restrict__ B,
             const float* __restrict__ bias, float* __restrict__ out)
{
    __shared__ unsigned short As[BM * BK];   // [m][k] row-major, 8 KB
    __shared__ unsigned short Bs[BN * BK];   // [n][k] row-major, 8 KB

    const int tid  = threadIdx.x;
    const int lane = tid & 63;
    const int wv   = tid >> 6;
    const int bn0  = blockIdx.x * BN;
    const int bm0  = blockIdx.y * BM;

    // staging geometry: chunk = wv*128 + j*64 + lane; row = chunk>>2, col = (lane&3)*8
    const int srow = wv * 32 + (lane >> 2);
    const int scol = (lane & 3) * 8;
    const unsigned short* ga0 = A + (size_t)(bm0 + srow) * K_DIM + scol;
    const unsigned short* ga1 = A + (size_t)(bm0 + srow + 16) * K_DIM + scol;
    const unsigned short* gb0 = B + (size_t)(bn0 + srow) * K_DIM + scol;
    const unsigned short* gb1 = B + (size_t)(bn0 + srow + 16) * K_DIM + scol;
    unsigned short* lA0 = &As[(wv * 128)      * 8];   // wave-uniform LDS bases
    unsigned short* lA1 = &As[(wv * 128 + 64) * 8];
    unsigned short* lB0 = &Bs[(wv * 128)      * 8];
    unsigned short* lB1 = &Bs[(wv * 128 + 64) * 8];

    const int quad = lane >> 4;
    const int l16  = lane & 15;
    const int wm   = (wv >> 1) * 64;
    const int wn   = (wv & 1) * 64;

    f32x4 acc[4][4] = {};

    for (int k0 = 0; k0 < K_DIM; k0 += BK) {
        __syncthreads();                       // prior reads done before overwrite
        GLD16(ga0, lA0);
        GLD16(ga1, lA1);
        GLD16(gb0, lB0);
        GLD16(gb1, lB1);
        ga0 += BK; ga1 += BK; gb0 += BK; gb1 += BK;
        __syncthreads();                       // drains vmcnt -> LDS populated

        bf16x8 af[4], bfr[4];
        #pragma unroll
        for (int mi = 0; mi < 4; ++mi)
            af[mi] = *reinterpret_cast<const bf16x8*>(&As[(wm + mi * 16 + l16) * BK + quad * 8]);
        #pragma unroll
        for (int ni = 0; ni < 4; ++ni)
            bfr[ni] = *reinterpret_cast<const bf16x8*>(&Bs[(wn + ni * 16 + l16) * BK + quad * 8]);
        #pragma unroll
        for (int mi = 0; mi < 4; ++mi) {
            #pragma unroll
            for (int ni = 0; ni < 4; ++ni)
                acc[mi][ni] = __builtin_amdgcn_mfma_f32_16x16x32_bf16(
                    af[mi], bfr[ni], acc[mi][ni], 0, 0, 0);
        }
    }

    // epilogue: D[m = quad*4 + r][n = l16] (verified C/D layout), fused bias
    #pragma unroll
    for (int ni = 0; ni < 4; ++ni) {
        const int n = bn0 + wn + ni * 16 + l16;
        const float bv = bias[n];
        #pragma unroll
        for (int mi = 0; mi < 4; ++mi) {
            #pragma unroll
            for (int r = 0; r < 4; ++r) {
                const int m = bm0 + wm + mi * 16 + quad * 4 + r;
                out[(size_t)m * N_DIM + n] = acc[mi][ni][r] + bv;
            }
        }
    }
}

// ---------------------------------------------------------------------------
// Fallback (round-2 passing kernel): fused dequant GEMM, used if ws too small.
__global__ __launch_bounds__(256, 2)
void l4b_mfma(const float* __restrict__ x, const int* __restrict__ qw,
              const float* __restrict__ scales, const int* __restrict__ qz,
              const float* __restrict__ bias, float* __restrict__ out)
{
    __shared__ unsigned short As[BM][BK];
    __shared__ unsigned short Bs[BK][BN];

    const int tid = threadIdx.x;
    const int bn0 = blockIdx.x * BN;
    const int bm0 = blockIdx.y * BM;
    const int ar = tid >> 3;
    const int ac = (tid & 7) << 2;
    const int bng = tid & 15;
    const int bkr = tid >> 4;
    const int nq  = (bn0 >> 3) + bng;

    float s8[8], zs8[8];
    {
        const unsigned zq = (unsigned)qz[nq];
        const float4 slo = *reinterpret_cast<const float4*>(scales + bn0 + bng * 8);
        const float4 shi = *reinterpret_cast<const float4*>(scales + bn0 + bng * 8 + 4);
        s8[0] = slo.x; s8[1] = slo.y; s8[2] = slo.z; s8[3] = slo.w;
        s8[4] = shi.x; s8[5] = shi.y; s8[6] = shi.z; s8[7] = shi.w;
        #pragma unroll
        for (int j = 0; j < 8; ++j)
            zs8[j] = (float)((zq >> (4 * j)) & 0xFu) * s8[j];
    }

    const int lane = tid & 63;
    const int wv   = tid >> 6;
    const int quad = lane >> 4;
    const int l16  = lane & 15;
    const int wm   = (wv >> 1) * 64;
    const int wn   = (wv & 1) * 64;

    f32x4 acc[4][4] = {};

    for (int k0 = 0; k0 < K_DIM; k0 += BK) {
        __syncthreads();
        #pragma unroll
        for (int p = 0; p < 4; ++p) {
            const int row = ar + p * 32;
            const float4 v = *reinterpret_cast<const float4*>(
                x + (size_t)(bm0 + row) * K_DIM + (k0 + ac));
            *reinterpret_cast<unsigned*>(&As[row][ac])     = pack2bf(v.x, v.y);
            *reinterpret_cast<unsigned*>(&As[row][ac + 2]) = pack2bf(v.z, v.w);
        }
        #pragma unroll
        for (int p = 0; p < 2; ++p) {
            const int kk = bkr + p * 16;
            const unsigned q  = (unsigned)qw[(size_t)(k0 + kk) * NPACK + nq];
            const unsigned qe = q & 0x0F0F0F0Fu;
            const unsigned qo = (q >> 4) & 0x0F0F0F0Fu;
            float f[8];
            f[0] = (float)(qe & 0xFFu);
            f[1] = (float)(qo & 0xFFu);
            f[2] = (float)((qe >> 8) & 0xFFu);
            f[3] = (float)((qo >> 8) & 0xFFu);
            f[4] = (float)((qe >> 16) & 0xFFu);
            f[5] = (float)((qo >> 16) & 0xFFu);
            f[6] = (float)((qe >> 24) & 0xFFu);
            f[7] = (float)((qo >> 24) & 0xFFu);
            #pragma unroll
            for (int j = 0; j < 4; ++j) {
                const float w0 = fmaf(f[2 * j],     s8[2 * j],     -zs8[2 * j]);
                const float w1 = fmaf(f[2 * j + 1], s8[2 * j + 1], -zs8[2 * j + 1]);
                *reinterpret_cast<unsigned*>(&Bs[kk][bng * 8 + 2 * j]) = pack2bf(w0, w1);
            }
        }
        __syncthreads();

        bf16x8 af[4], bfr[4];
        #pragma unroll
        for (int mi = 0; mi < 4; ++mi)
            af[mi] = *reinterpret_cast<const bf16x8*>(&As[wm + mi * 16 + l16][quad * 8]);
        #pragma unroll
        for (int ni = 0; ni < 4; ++ni) {
            u16x8 bu;
            #pragma unroll
            for (int jj = 0; jj < 8; ++jj)
                bu[jj] = Bs[quad * 8 + jj][wn + ni * 16 + l16];
            bfr[ni] = __builtin_bit_cast(bf16x8, bu);
        }
        #pragma unroll
        for (int mi = 0; mi < 4; ++mi) {
            #pragma unroll
            for (int ni = 0; ni < 4; ++ni)
                acc[mi][ni] = __builtin_amdgcn_mfma_f32_16x16x32_bf16(
                    af[mi], bfr[ni], acc[mi][ni], 0, 0, 0);
        }
    }

    #pragma unroll
    for (int ni = 0; ni < 4; ++ni) {
        const int n = bn0 + wn + ni * 16 + l16;
        const float bv = bias[n];
        #pragma unroll
        for (int mi = 0; mi < 4; ++mi) {
            #pragma unroll
            for (int r = 0; r < 4; ++r) {
                const int m = bm0 + wm + mi * 16 + quad * 4 + r;
                out[(size_t)m * N_DIM + n] = acc[mi][ni][r] + bv;
            }
        }
    }
}

extern "C" void kernel_launch(void* const* d_in, const int* in_sizes, int n_in,
                              void* d_out, int out_size, void* d_ws, size_t ws_size,
                              hipStream_t stream)
{
    (void)n_in; (void)out_size;
    const float* x      = (const float*)d_in[0];
    const int*   qw     = (const int*)d_in[1];
    const float* scales = (const float*)d_in[2];
    const int*   qz     = (const int*)d_in[3];
    const float* bias   = (const float*)d_in[4];
    float* out = (float*)d_out;

    const int M = in_sizes[0] / K_DIM;                    // 8192
    const size_t xb_bytes = (size_t)M * K_DIM * 2;        // 64 MB
    const size_t wt_bytes = (size_t)N_DIM * K_DIM * 2;    // 90 MB

    if (ws_size >= xb_bytes + wt_bytes) {
        unsigned short* xb = (unsigned short*)d_ws;
        unsigned short* wt = (unsigned short*)((char*)d_ws + xb_bytes);
        convert_x<<<(int)(((size_t)M * K_DIM) / (256 * 8)), 256, 0, stream>>>(x, xb);
        dequant_w<<<dim3(N_DIM / 64, K_DIM / 64), 256, 0, stream>>>(qw, scales, qz, wt);
        gemm_bt<<<dim3(N_DIM / BN, M / BM), 256, 0, stream>>>(xb, wt, bias, out);
    } else {
        dim3 grid(N_DIM / BN, M / BM);
        l4b_mfma<<<grid, dim3(256, 1, 1), 0, stream>>>(x, qw, scales, qz, bias, out);
    }
}